// Round 2
// baseline (980.165 us; speedup 1.0000x reference)
//
#include <hip/hip_runtime.h>

// ---- problem constants ----
#define P_   512
#define NB_  16
#define D_   2048
#define DB_  128
#define H_   512
#define B_   8
#define N_   4096

typedef __attribute__((ext_vector_type(8))) short short8;
typedef __attribute__((ext_vector_type(4))) float f32x4;

static __device__ __forceinline__ short f2bf(float x) {
    union { float f; unsigned u; } v; v.f = x;
    unsigned r = (v.u + 0x7FFF + ((v.u >> 16) & 1)) >> 16;   // RNE
    return (short)r;
}

// ---------------------------------------------------------------------------
// Kernel 1: fp32 -> bf16 conversion of mem_params + w1..w4 (layouts unchanged;
// w[i] is [fan_out][fan_in] which is exactly the [N][K] B-operand layout).
// dst order: memp(1048576) w1(65536) w2(262144) w3(262144) w4(65536)
// ---------------------------------------------------------------------------
__global__ __launch_bounds__(256) void k_convert(
    const float* __restrict__ memp, const float* __restrict__ w1,
    const float* __restrict__ w2, const float* __restrict__ w3,
    const float* __restrict__ w4, short* __restrict__ dst)
{
    const int total = 1048576 + 65536 + 262144 + 262144 + 65536;
    for (int i = blockIdx.x * 256 + threadIdx.x; i < total; i += gridDim.x * 256) {
        int j = i; float v;
        if (j < 1048576) v = memp[j];
        else {
            j -= 1048576;
            if (j < 65536) v = w1[j];
            else { j -= 65536;
                if (j < 262144) v = w2[j];
                else { j -= 262144;
                    if (j < 262144) v = w3[j];
                    else v = w4[j - 262144];
                }
            }
        }
        dst[i] = f2bf(v);
    }
}

// ---------------------------------------------------------------------------
// MFMA GEMM: Out[M][Nn] = act( A[M][K] @ Bw[Nn][K]^T + bias )
// MODE 0: relu, bf16 store to Out[M][Nn]
// MODE 1: block-LN epilogue (BM=64, BN=128=Nn): writes mem bf16 [NB][P][DB]
// ---------------------------------------------------------------------------
template<int BM, int BN, int K, int MODE>
__global__ __launch_bounds__(256) void k_gemm(
    const short* __restrict__ A, const short* __restrict__ Bw,
    const float* __restrict__ bias, short* __restrict__ Out, int Nn)
{
    constexpr int MT = BM / 64;
    constexpr int NT = BN / 16;
    __shared__ short As[BM * 72];
    __shared__ short Bs[BN * 72];

    const int tid = threadIdx.x;
    const int w = tid >> 6, l = tid & 63;
    const int lr = l & 15, lq = l >> 4;
    const int nblk = (MODE == 1) ? 1 : (512 / BN);
    const int m0 = (blockIdx.x / nblk) * BM;
    const int n0 = (blockIdx.x % nblk) * BN;

    f32x4 acc[MT][NT] = {};

    for (int k0 = 0; k0 < K; k0 += 64) {
        #pragma unroll
        for (int i = tid * 8; i < BM * 64; i += 2048) {
            int r = i >> 6, c = i & 63;
            *(short8*)&As[r * 72 + c] = *(const short8*)&A[(size_t)(m0 + r) * K + k0 + c];
        }
        #pragma unroll
        for (int i = tid * 8; i < BN * 64; i += 2048) {
            int r = i >> 6, c = i & 63;
            *(short8*)&Bs[r * 72 + c] = *(const short8*)&Bw[(size_t)(n0 + r) * K + k0 + c];
        }
        __syncthreads();
        #pragma unroll
        for (int ks = 0; ks < 2; ++ks) {
            short8 bf[NT];
            #pragma unroll
            for (int nt = 0; nt < NT; ++nt)
                bf[nt] = *(const short8*)&Bs[(nt * 16 + lr) * 72 + ks * 32 + lq * 8];
            #pragma unroll
            for (int mt = 0; mt < MT; ++mt) {
                short8 af = *(const short8*)&As[((w * MT + mt) * 16 + lr) * 72 + ks * 32 + lq * 8];
                #pragma unroll
                for (int nt = 0; nt < NT; ++nt)
                    acc[mt][nt] = __builtin_amdgcn_mfma_f32_16x16x32_bf16(af, bf[nt], acc[mt][nt], 0, 0, 0);
            }
        }
        __syncthreads();
    }

    if (MODE == 0) {
        #pragma unroll
        for (int mt = 0; mt < MT; ++mt) {
            #pragma unroll
            for (int nt = 0; nt < NT; ++nt) {
                float bv = bias[n0 + nt * 16 + lr];
                #pragma unroll
                for (int r = 0; r < 4; ++r) {
                    int row = m0 + (w * MT + mt) * 16 + lq * 4 + r;
                    float v = acc[mt][nt][r] + bv;
                    v = fmaxf(v, 0.f);
                    Out[(size_t)row * Nn + n0 + nt * 16 + lr] = f2bf(v);
                }
            }
        }
    } else {
        float vals[NT][4];
        float sum[4] = {0,0,0,0}, sq[4] = {0,0,0,0};
        #pragma unroll
        for (int nt = 0; nt < NT; ++nt) {
            float bv = bias[nt * 16 + lr];
            #pragma unroll
            for (int r = 0; r < 4; ++r) {
                float v = acc[0][nt][r] + bv;
                vals[nt][r] = v; sum[r] += v; sq[r] += v * v;
            }
        }
        #pragma unroll
        for (int m = 1; m < 16; m <<= 1) {
            #pragma unroll
            for (int r = 0; r < 4; ++r) {
                sum[r] += __shfl_xor(sum[r], m);
                sq[r]  += __shfl_xor(sq[r], m);
            }
        }
        #pragma unroll
        for (int r = 0; r < 4; ++r) {
            float mu = sum[r] * (1.f / 128.f);
            float var = sq[r] * (1.f / 128.f) - mu * mu;
            float rstd = rsqrtf(var + 1e-5f);
            int vrow = m0 + w * 16 + lq * 4 + r;          // vector id = p*NB + nb
            int nb = vrow & 15, p = vrow >> 4;
            #pragma unroll
            for (int nt = 0; nt < NT; ++nt)
                Out[((size_t)(nb * 512 + p)) * 128 + nt * 16 + lr] = f2bf((vals[nt][r] - mu) * rstd);
        }
    }
}

// ---------------------------------------------------------------------------
// mem [NB][P][DB] -> memT [NB][DB][P]  (LDS-tiled 64x64 transpose)
// ---------------------------------------------------------------------------
__global__ __launch_bounds__(256) void k_transpose(const short* __restrict__ mem, short* __restrict__ memT)
{
    int bid = blockIdx.x;                 // 256 = 16 nb * 8 ptile * 2 dtile
    int nb = bid >> 4, pt = (bid >> 1) & 7, dt = bid & 1;
    __shared__ short t[64 * 72];
    const short* src = mem + ((size_t)(nb * 512 + pt * 64)) * 128 + dt * 64;
    for (int i = threadIdx.x * 8; i < 64 * 64; i += 2048) {
        int p = i >> 6, d = i & 63;
        *(short8*)&t[p * 72 + d] = *(const short8*)&src[(size_t)p * 128 + d];
    }
    __syncthreads();
    short* dst = memT + ((size_t)(nb * 128 + dt * 64)) * 512 + pt * 64;
    for (int i = threadIdx.x * 8; i < 64 * 64; i += 2048) {
        int d = i >> 6, p = i & 63;
        short8 v;
        #pragma unroll
        for (int j = 0; j < 8; ++j) v[j] = t[(p + j) * 72 + d];
        *(short8*)&dst[(size_t)d * 512 + p] = v;
    }
}

// ---------------------------------------------------------------------------
// Fused attention, BARRIER-FREE version.
// Per workgroup = (b, h, 128-query tile); per wave = 32 query rows.
// All LDS is wave-private (same-wave DS write->read, in-order, no barrier):
//   qs[w]: [32][136] bf16 staged queries (phase A), then dead
//   pb[w]: [32][72]  exp(S) C-layout -> A-layout round trip
// K and V^T fragments are loaded DIRECTLY from global (mem slice is
// 256 KB/head, L2-resident) in MFMA B-layout -> no cooperative staging,
// no __syncthreads anywhere.
// Softmax without max-subtraction: |score| <= sqrt(128), exp safe in fp32.
// ---------------------------------------------------------------------------
__global__ __launch_bounds__(256, 3) void k_attn(
    const float* __restrict__ q, const short* __restrict__ mem,
    const short* __restrict__ memT, float* __restrict__ out)
{
    __shared__ short qs[4 * 32 * 136];   // 34816 B, wave-private slices
    __shared__ short pb[4 * 32 * 72];    // 18432 B, wave-private slices

    const int x = blockIdx.x;
    const int qt = x & 31, h = (x >> 5) & 15, b = x >> 9;
    const int tid = threadIdx.x, w = tid >> 6, l = tid & 63;
    const int q0 = qt * 128;
    const int lr = l & 15, lq = l >> 4;

    short* qsw = qs + w * (32 * 136);
    short* pbw = pb + w * (32 * 72);

    // ---- Phase A: query block-LN (+ DB^-0.5 fold) -> bf16 qs (wave-private)
    const float* qbase = q + ((size_t)(b * N_ + q0)) * D_ + h * DB_;
    #pragma unroll
    for (int g = 0; g < 4; ++g) {
        int lrow = g * 8 + (l >> 3);
        int c0 = (l & 7) * 16;
        const float* rp = qbase + (size_t)(w * 32 + lrow) * D_ + c0;
        float x16[16];
        float s = 0.f, sq2 = 0.f;
        #pragma unroll
        for (int u = 0; u < 16; u += 4) {
            f32x4 v4 = *(const f32x4*)(rp + u);
            #pragma unroll
            for (int j = 0; j < 4; ++j) { float v = v4[j]; x16[u + j] = v; s += v; sq2 += v * v; }
        }
        s += __shfl_xor(s, 1);  sq2 += __shfl_xor(sq2, 1);
        s += __shfl_xor(s, 2);  sq2 += __shfl_xor(sq2, 2);
        s += __shfl_xor(s, 4);  sq2 += __shfl_xor(sq2, 4);
        float mu = s * (1.f / 128.f);
        float var = sq2 * (1.f / 128.f) - mu * mu;
        float rstd = rsqrtf(var + 1e-5f) * 0.08838834764831845f;  // fold DB^-0.5
        short tmp[16];
        #pragma unroll
        for (int u = 0; u < 16; ++u) tmp[u] = f2bf((x16[u] - mu) * rstd);
        *(short8*)&qsw[lrow * 136 + c0]     = *(short8*)&tmp[0];
        *(short8*)&qsw[lrow * 136 + c0 + 8] = *(short8*)&tmp[8];
    }

    f32x4 o[2][8] = {};
    float rs[2][4] = {};
    const short* memh  = mem  + (size_t)h * 512 * 128;
    const short* memTh = memT + (size_t)h * 128 * 512;

    for (int kt = 0; kt < 8; ++kt) {
        // Q fragments for this wave (same-wave LDS read; in-order DS)
        short8 qf[2][4];
        #pragma unroll
        for (int mt = 0; mt < 2; ++mt)
            #pragma unroll
            for (int ks = 0; ks < 4; ++ks)
                qf[mt][ks] = *(const short8*)&qsw[(mt * 16 + lr) * 136 + ks * 32 + lq * 8];

        // S = Q·K^T ; K-frags straight from L2, loaded once per (nt,ks)
        #pragma unroll
        for (int nt = 0; nt < 4; ++nt) {
            f32x4 s0 = {}, s1 = {};
            #pragma unroll
            for (int ks = 0; ks < 4; ++ks) {
                short8 bf = *(const short8*)&memh[(size_t)(kt * 64 + nt * 16 + lr) * 128 + ks * 32 + lq * 8];
                s0 = __builtin_amdgcn_mfma_f32_16x16x32_bf16(qf[0][ks], bf, s0, 0, 0, 0);
                s1 = __builtin_amdgcn_mfma_f32_16x16x32_bf16(qf[1][ks], bf, s1, 0, 0, 0);
            }
            #pragma unroll
            for (int r = 0; r < 4; ++r) {
                float e0 = __expf(s0[r]);
                float e1 = __expf(s1[r]);
                rs[0][r] += e0;
                rs[1][r] += e1;
                pbw[(lq * 4 + r) * 72 + nt * 16 + lr]        = f2bf(e0);
                pbw[(16 + lq * 4 + r) * 72 + nt * 16 + lr]   = f2bf(e1);
            }
        }

        // P A-frags (same-wave LDS read), then O += P·V^T (V-frags from L2)
        short8 af[2][2];
        #pragma unroll
        for (int mt = 0; mt < 2; ++mt)
            #pragma unroll
            for (int k2 = 0; k2 < 2; ++k2)
                af[mt][k2] = *(const short8*)&pbw[(mt * 16 + lr) * 72 + k2 * 32 + lq * 8];
        #pragma unroll
        for (int ntd = 0; ntd < 8; ++ntd) {
            #pragma unroll
            for (int k2 = 0; k2 < 2; ++k2) {
                short8 bf = *(const short8*)&memTh[(size_t)(ntd * 16 + lr) * 512 + kt * 64 + k2 * 32 + lq * 8];
                o[0][ntd] = __builtin_amdgcn_mfma_f32_16x16x32_bf16(af[0][k2], bf, o[0][ntd], 0, 0, 0);
                o[1][ntd] = __builtin_amdgcn_mfma_f32_16x16x32_bf16(af[1][k2], bf, o[1][ntd], 0, 0, 0);
            }
        }
    }

    // rowsum across the 16 lanes holding each row, then normalize + store
    #pragma unroll
    for (int mt = 0; mt < 2; ++mt)
        #pragma unroll
        for (int r = 0; r < 4; ++r) {
            float v = rs[mt][r];
            v += __shfl_xor(v, 1); v += __shfl_xor(v, 2);
            v += __shfl_xor(v, 4); v += __shfl_xor(v, 8);
            rs[mt][r] = 1.f / v;
        }
    float* ob = out + ((size_t)(b * N_ + q0)) * D_ + h * DB_;
    #pragma unroll
    for (int mt = 0; mt < 2; ++mt)
        #pragma unroll
        for (int ntd = 0; ntd < 8; ++ntd)
            #pragma unroll
            for (int r = 0; r < 4; ++r)
                ob[(size_t)(w * 32 + mt * 16 + lq * 4 + r) * D_ + ntd * 16 + lr] = o[mt][ntd][r] * rs[mt][r];
}

// ---------------------------------------------------------------------------
extern "C" void kernel_launch(void* const* d_in, const int* in_sizes, int n_in,
                              void* d_out, int out_size, void* d_ws, size_t ws_size,
                              hipStream_t stream) {
    const float* queries = (const float*)d_in[0];
    const float* memp    = (const float*)d_in[1];
    const float* w1 = (const float*)d_in[2]; const float* b1 = (const float*)d_in[3];
    const float* w2 = (const float*)d_in[4]; const float* b2 = (const float*)d_in[5];
    const float* w3 = (const float*)d_in[6]; const float* b3 = (const float*)d_in[7];
    const float* w4 = (const float*)d_in[8]; const float* b4 = (const float*)d_in[9];
    float* out = (float*)d_out;

    short* ws      = (short*)d_ws;
    short* memp_b  = ws;                       // 1048576
    short* w1b     = memp_b + 1048576;         // 65536
    short* w2b     = w1b + 65536;              // 262144
    short* w3b     = w2b + 262144;             // 262144
    short* w4b     = w3b + 262144;             // 65536
    short* act1    = w4b + 65536;              // 8192*512
    short* act2    = act1 + 4194304;           // 8192*512
    short* memb    = act2 + 4194304;           // 16*512*128
    short* memTb   = memb + 1048576;           // 16*128*512

    k_convert<<<2048, 256, 0, stream>>>(memp, w1, w2, w3, w4, ws);
    k_gemm<128, 128, 128, 0><<<256, 256, 0, stream>>>(memp_b, w1b, b1, act1, 512);
    k_gemm<128, 128, 512, 0><<<256, 256, 0, stream>>>(act1, w2b, b2, act2, 512);
    k_gemm<128, 128, 512, 0><<<256, 256, 0, stream>>>(act2, w3b, b3, act1, 512);
    k_gemm<64, 128, 512, 1><<<128, 256, 0, stream>>>(act1, w4b, b4, memb, 128);
    k_transpose<<<256, 256, 0, stream>>>(memb, memTb);
    k_attn<<<4096, 256, 0, stream>>>(queries, memb, memTb, out);
}

// Round 3
// 729.929 us; speedup vs baseline: 1.3428x; 1.3428x over previous
//
#include <hip/hip_runtime.h>

// ---- problem constants ----
#define P_   512
#define NB_  16
#define D_   2048
#define DB_  128
#define H_   512
#define B_   8
#define N_   4096

typedef __attribute__((ext_vector_type(8))) short short8;
typedef __attribute__((ext_vector_type(4))) float f32x4;

static __device__ __forceinline__ short f2bf(float x) {
    union { float f; unsigned u; } v; v.f = x;
    unsigned r = (v.u + 0x7FFF + ((v.u >> 16) & 1)) >> 16;   // RNE
    return (short)r;
}

// ---------------------------------------------------------------------------
// Kernel 1: fp32 -> bf16 conversion of mem_params + w1..w4
// ---------------------------------------------------------------------------
__global__ __launch_bounds__(256) void k_convert(
    const float* __restrict__ memp, const float* __restrict__ w1,
    const float* __restrict__ w2, const float* __restrict__ w3,
    const float* __restrict__ w4, short* __restrict__ dst)
{
    const int total = 1048576 + 65536 + 262144 + 262144 + 65536;
    for (int i = blockIdx.x * 256 + threadIdx.x; i < total; i += gridDim.x * 256) {
        int j = i; float v;
        if (j < 1048576) v = memp[j];
        else {
            j -= 1048576;
            if (j < 65536) v = w1[j];
            else { j -= 65536;
                if (j < 262144) v = w2[j];
                else { j -= 262144;
                    if (j < 262144) v = w3[j];
                    else v = w4[j - 262144];
                }
            }
        }
        dst[i] = f2bf(v);
    }
}

// ---------------------------------------------------------------------------
// MFMA GEMM: Out[M][Nn] = act( A[M][K] @ Bw[Nn][K]^T + bias )
// MODE 0: relu, bf16 store. MODE 1: block-LN epilogue -> mem bf16 [NB][P][DB]
// ---------------------------------------------------------------------------
template<int BM, int BN, int K, int MODE>
__global__ __launch_bounds__(256) void k_gemm(
    const short* __restrict__ A, const short* __restrict__ Bw,
    const float* __restrict__ bias, short* __restrict__ Out, int Nn)
{
    constexpr int MT = BM / 64;
    constexpr int NT = BN / 16;
    __shared__ short As[BM * 72];
    __shared__ short Bs[BN * 72];

    const int tid = threadIdx.x;
    const int w = tid >> 6, l = tid & 63;
    const int lr = l & 15, lq = l >> 4;
    const int nblk = (MODE == 1) ? 1 : (512 / BN);
    const int m0 = (blockIdx.x / nblk) * BM;
    const int n0 = (blockIdx.x % nblk) * BN;

    f32x4 acc[MT][NT] = {};

    for (int k0 = 0; k0 < K; k0 += 64) {
        #pragma unroll
        for (int i = tid * 8; i < BM * 64; i += 2048) {
            int r = i >> 6, c = i & 63;
            *(short8*)&As[r * 72 + c] = *(const short8*)&A[(size_t)(m0 + r) * K + k0 + c];
        }
        #pragma unroll
        for (int i = tid * 8; i < BN * 64; i += 2048) {
            int r = i >> 6, c = i & 63;
            *(short8*)&Bs[r * 72 + c] = *(const short8*)&Bw[(size_t)(n0 + r) * K + k0 + c];
        }
        __syncthreads();
        #pragma unroll
        for (int ks = 0; ks < 2; ++ks) {
            short8 bf[NT];
            #pragma unroll
            for (int nt = 0; nt < NT; ++nt)
                bf[nt] = *(const short8*)&Bs[(nt * 16 + lr) * 72 + ks * 32 + lq * 8];
            #pragma unroll
            for (int mt = 0; mt < MT; ++mt) {
                short8 af = *(const short8*)&As[((w * MT + mt) * 16 + lr) * 72 + ks * 32 + lq * 8];
                #pragma unroll
                for (int nt = 0; nt < NT; ++nt)
                    acc[mt][nt] = __builtin_amdgcn_mfma_f32_16x16x32_bf16(af, bf[nt], acc[mt][nt], 0, 0, 0);
            }
        }
        __syncthreads();
    }

    if (MODE == 0) {
        #pragma unroll
        for (int mt = 0; mt < MT; ++mt) {
            #pragma unroll
            for (int nt = 0; nt < NT; ++nt) {
                float bv = bias[n0 + nt * 16 + lr];
                #pragma unroll
                for (int r = 0; r < 4; ++r) {
                    int row = m0 + (w * MT + mt) * 16 + lq * 4 + r;
                    float v = acc[mt][nt][r] + bv;
                    v = fmaxf(v, 0.f);
                    Out[(size_t)row * Nn + n0 + nt * 16 + lr] = f2bf(v);
                }
            }
        }
    } else {
        float vals[NT][4];
        float sum[4] = {0,0,0,0}, sq[4] = {0,0,0,0};
        #pragma unroll
        for (int nt = 0; nt < NT; ++nt) {
            float bv = bias[nt * 16 + lr];
            #pragma unroll
            for (int r = 0; r < 4; ++r) {
                float v = acc[0][nt][r] + bv;
                vals[nt][r] = v; sum[r] += v; sq[r] += v * v;
            }
        }
        #pragma unroll
        for (int m = 1; m < 16; m <<= 1) {
            #pragma unroll
            for (int r = 0; r < 4; ++r) {
                sum[r] += __shfl_xor(sum[r], m);
                sq[r]  += __shfl_xor(sq[r], m);
            }
        }
        #pragma unroll
        for (int r = 0; r < 4; ++r) {
            float mu = sum[r] * (1.f / 128.f);
            float var = sq[r] * (1.f / 128.f) - mu * mu;
            float rstd = rsqrtf(var + 1e-5f);
            int vrow = m0 + w * 16 + lq * 4 + r;          // vector id = p*NB + nb
            int nb = vrow & 15, p = vrow >> 4;
            #pragma unroll
            for (int nt = 0; nt < NT; ++nt)
                Out[((size_t)(nb * 512 + p)) * 128 + nt * 16 + lr] = f2bf((vals[nt][r] - mu) * rstd);
        }
    }
}

// ---------------------------------------------------------------------------
// mem [NB][P][DB] -> memT [NB][DB][P]  (LDS-tiled 64x64 transpose)
// ---------------------------------------------------------------------------
__global__ __launch_bounds__(256) void k_transpose(const short* __restrict__ mem, short* __restrict__ memT)
{
    int bid = blockIdx.x;                 // 256 = 16 nb * 8 ptile * 2 dtile
    int nb = bid >> 4, pt = (bid >> 1) & 7, dt = bid & 1;
    __shared__ short t[64 * 72];
    const short* src = mem + ((size_t)(nb * 512 + pt * 64)) * 128 + dt * 64;
    for (int i = threadIdx.x * 8; i < 64 * 64; i += 2048) {
        int p = i >> 6, d = i & 63;
        *(short8*)&t[p * 72 + d] = *(const short8*)&src[(size_t)p * 128 + d];
    }
    __syncthreads();
    short* dst = memT + ((size_t)(nb * 128 + dt * 64)) * 512 + pt * 64;
    for (int i = threadIdx.x * 8; i < 64 * 64; i += 2048) {
        int d = i >> 6, p = i & 63;
        short8 v;
        #pragma unroll
        for (int j = 0; j < 8; ++j) v[j] = t[(p + j) * 72 + d];
        *(short8*)&dst[(size_t)d * 512 + p] = v;
    }
}

// ---------------------------------------------------------------------------
// Fused attention v3: cooperative swizzled K/V LDS staging + reg-prefetch
// pipeline; Q loaded directly in frag layout (shuffle block-LN, no Q LDS).
//   ktb: K tile [64p][128d] bf16, XOR-swizzled 16B chunks   (16 KB)
//   vtb: V^T tile [128d][64p] bf16, XOR-swizzled             (16 KB)
//   pb : per-wave exp(S) C->A layout round trip, stride 72   (18 KB)
// Total 51200 B -> 3 blocks/CU. Softmax without max-subtraction
// (|score| <= sqrt(128)).
// ---------------------------------------------------------------------------
__device__ __forceinline__ int kswz(int p, int d) {          // ktb: row 128 shorts, 16 chunks
    return p * 128 + ((((d >> 3) ^ (p & 15)) << 3) | (d & 7));
}
__device__ __forceinline__ int vswz(int d, int p) {          // vtb: row 64 shorts, 8 chunks
    return d * 64 + ((((p >> 3) ^ (d & 7)) << 3) | (p & 7));
}

__global__ __launch_bounds__(256, 3) void k_attn(
    const float* __restrict__ q, const short* __restrict__ mem,
    const short* __restrict__ memT, float* __restrict__ out)
{
    __shared__ short ktb[64 * 128];      // 16384 B
    __shared__ short vtb[128 * 64];      // 16384 B
    __shared__ short pb[4 * 32 * 72];    // 18432 B (wave-private slices)

    const int x = blockIdx.x;
    const int qt = x & 31, h = (x >> 5) & 15, b = x >> 9;
    const int tid = threadIdx.x, w = tid >> 6, l = tid & 63;
    const int q0 = qt * 128;
    const int lr = l & 15, lq = l >> 4;
    short* pbw = pb + w * (32 * 72);

    // ---- Q directly in A-frag layout + shuffle block-LN (+ DB^-0.5) ----
    const float* qbase = q + ((size_t)(b * N_ + q0)) * D_ + h * DB_;
    short8 qf[2][4];
    #pragma unroll
    for (int mt = 0; mt < 2; ++mt) {
        const float* rp = qbase + (size_t)(w * 32 + mt * 16 + lr) * D_ + lq * 8;
        float xv[32];
        float s = 0.f, sq2 = 0.f;
        #pragma unroll
        for (int ks = 0; ks < 4; ++ks) {
            f32x4 a = *(const f32x4*)(rp + ks * 32);
            f32x4 c = *(const f32x4*)(rp + ks * 32 + 4);
            #pragma unroll
            for (int j = 0; j < 4; ++j) {
                xv[ks * 8 + j]     = a[j]; s += a[j]; sq2 += a[j] * a[j];
                xv[ks * 8 + 4 + j] = c[j]; s += c[j]; sq2 += c[j] * c[j];
            }
        }
        // lanes holding the same row differ in bits 4-5
        s += __shfl_xor(s, 16);  sq2 += __shfl_xor(sq2, 16);
        s += __shfl_xor(s, 32);  sq2 += __shfl_xor(sq2, 32);
        float mu = s * (1.f / 128.f);
        float var = sq2 * (1.f / 128.f) - mu * mu;
        float rstd = rsqrtf(var + 1e-5f) * 0.08838834764831845f;  // fold DB^-0.5
        #pragma unroll
        for (int ks = 0; ks < 4; ++ks) {
            short8 t;
            #pragma unroll
            for (int j = 0; j < 8; ++j) t[j] = f2bf((xv[ks * 8 + j] - mu) * rstd);
            qf[mt][ks] = t;
        }
    }

    const short* memh  = mem  + (size_t)h * 512 * 128;
    const short* memTh = memT + (size_t)h * 128 * 512;

    // ---- prefetch tile 0 into registers ----
    short8 pk[4], pv[4];
    #pragma unroll
    for (int u = 0; u < 4; ++u) {
        int i = tid * 8 + u * 2048;
        pk[u] = *(const short8*)&memh[(size_t)(i >> 7) * 128 + (i & 127)];
        pv[u] = *(const short8*)&memTh[(size_t)(i >> 6) * 512 + (i & 63)];
    }

    f32x4 o[2][8] = {};
    float rs[2][4] = {};

    for (int kt = 0; kt < 8; ++kt) {
        // write prefetched tile to LDS (swizzled)
        #pragma unroll
        for (int u = 0; u < 4; ++u) {
            int i = tid * 8 + u * 2048;
            *(short8*)&ktb[kswz(i >> 7, i & 127)] = pk[u];
            *(short8*)&vtb[vswz(i >> 6, i & 63)]  = pv[u];
        }
        __syncthreads();

        // issue prefetch of tile kt+1 (lands during compute below)
        if (kt < 7) {
            #pragma unroll
            for (int u = 0; u < 4; ++u) {
                int i = tid * 8 + u * 2048;
                pk[u] = *(const short8*)&memh[(size_t)((kt + 1) * 64 + (i >> 7)) * 128 + (i & 127)];
                pv[u] = *(const short8*)&memTh[(size_t)(i >> 6) * 512 + (kt + 1) * 64 + (i & 63)];
            }
        }

        // S = Q·K^T, exp, stash to pb (own-wave region, no barrier needed)
        #pragma unroll
        for (int nt = 0; nt < 4; ++nt) {
            f32x4 s0 = {}, s1 = {};
            #pragma unroll
            for (int ks = 0; ks < 4; ++ks) {
                short8 bf = *(const short8*)&ktb[kswz(nt * 16 + lr, ks * 32 + lq * 8)];
                s0 = __builtin_amdgcn_mfma_f32_16x16x32_bf16(qf[0][ks], bf, s0, 0, 0, 0);
                s1 = __builtin_amdgcn_mfma_f32_16x16x32_bf16(qf[1][ks], bf, s1, 0, 0, 0);
            }
            #pragma unroll
            for (int r = 0; r < 4; ++r) {
                float e0 = __expf(s0[r]);
                float e1 = __expf(s1[r]);
                rs[0][r] += e0;
                rs[1][r] += e1;
                pbw[(lq * 4 + r) * 72 + nt * 16 + lr]      = f2bf(e0);
                pbw[(16 + lq * 4 + r) * 72 + nt * 16 + lr] = f2bf(e1);
            }
        }

        // P A-frags (same-wave LDS), O += P·V^T
        short8 af[2][2];
        #pragma unroll
        for (int mt = 0; mt < 2; ++mt)
            #pragma unroll
            for (int k2 = 0; k2 < 2; ++k2)
                af[mt][k2] = *(const short8*)&pbw[(mt * 16 + lr) * 72 + k2 * 32 + lq * 8];
        #pragma unroll
        for (int ntd = 0; ntd < 8; ++ntd) {
            #pragma unroll
            for (int k2 = 0; k2 < 2; ++k2) {
                short8 bf = *(const short8*)&vtb[vswz(ntd * 16 + lr, k2 * 32 + lq * 8)];
                o[0][ntd] = __builtin_amdgcn_mfma_f32_16x16x32_bf16(af[0][k2], bf, o[0][ntd], 0, 0, 0);
                o[1][ntd] = __builtin_amdgcn_mfma_f32_16x16x32_bf16(af[1][k2], bf, o[1][ntd], 0, 0, 0);
            }
        }
        __syncthreads();   // protect LDS before next iteration's staging write
    }

    // rowsum across lanes sharing each row, normalize + store
    #pragma unroll
    for (int mt = 0; mt < 2; ++mt)
        #pragma unroll
        for (int r = 0; r < 4; ++r) {
            float v = rs[mt][r];
            v += __shfl_xor(v, 1); v += __shfl_xor(v, 2);
            v += __shfl_xor(v, 4); v += __shfl_xor(v, 8);
            rs[mt][r] = 1.f / v;
        }
    float* ob = out + ((size_t)(b * N_ + q0)) * D_ + h * DB_;
    #pragma unroll
    for (int mt = 0; mt < 2; ++mt)
        #pragma unroll
        for (int ntd = 0; ntd < 8; ++ntd)
            #pragma unroll
            for (int r = 0; r < 4; ++r)
                ob[(size_t)(w * 32 + mt * 16 + lq * 4 + r) * D_ + ntd * 16 + lr] = o[mt][ntd][r] * rs[mt][r];
}

// ---------------------------------------------------------------------------
extern "C" void kernel_launch(void* const* d_in, const int* in_sizes, int n_in,
                              void* d_out, int out_size, void* d_ws, size_t ws_size,
                              hipStream_t stream) {
    const float* queries = (const float*)d_in[0];
    const float* memp    = (const float*)d_in[1];
    const float* w1 = (const float*)d_in[2]; const float* b1 = (const float*)d_in[3];
    const float* w2 = (const float*)d_in[4]; const float* b2 = (const float*)d_in[5];
    const float* w3 = (const float*)d_in[6]; const float* b3 = (const float*)d_in[7];
    const float* w4 = (const float*)d_in[8]; const float* b4 = (const float*)d_in[9];
    float* out = (float*)d_out;

    short* ws      = (short*)d_ws;
    short* memp_b  = ws;                       // 1048576
    short* w1b     = memp_b + 1048576;         // 65536
    short* w2b     = w1b + 65536;              // 262144
    short* w3b     = w2b + 262144;             // 262144
    short* w4b     = w3b + 262144;             // 65536
    short* act1    = w4b + 65536;              // 8192*512
    short* act2    = act1 + 4194304;           // 8192*512
    short* memb    = act2 + 4194304;           // 16*512*128
    short* memTb   = memb + 1048576;           // 16*128*512

    k_convert<<<2048, 256, 0, stream>>>(memp, w1, w2, w3, w4, ws);
    k_gemm<128, 128, 128, 0><<<256, 256, 0, stream>>>(memp_b, w1b, b1, act1, 512);
    k_gemm<128, 128, 512, 0><<<256, 256, 0, stream>>>(act1, w2b, b2, act2, 512);
    k_gemm<128, 128, 512, 0><<<256, 256, 0, stream>>>(act2, w3b, b3, act1, 512);
    k_gemm<64, 128, 512, 1><<<128, 256, 0, stream>>>(act1, w4b, b4, memb, 128);
    k_transpose<<<256, 256, 0, stream>>>(memb, memTb);
    k_attn<<<4096, 256, 0, stream>>>(queries, memb, memTb, out);
}